// Round 10
// baseline (1684641.406 us; speedup 1.0000x reference)
//
#include <hip/hip_runtime.h>
#include <hip/hip_fp16.h>
#include <math.h>

typedef unsigned int  uint32;
typedef unsigned short u16;

#define NWG 65          // wg 0: GRU WG; wg 1-64: helper WGs
#define NTH 256

// workspace layout (bytes)
#define OFF_XP   1024u                        // xp [256][768] f32 (b_ih + b_hh[r,z] folded)
#define OFF_XC   (OFF_XP + 256u*768u*4u)      // seq / Xr [256][256] f32
#define OFF_D    (OFF_XC + 256u*256u*4u)      // dec_out row [256][256] f32
#define OFF_Y1   (OFF_D  + 256u*256u*4u)      // y1 [128][512] f32

typedef _Float16 half2_t __attribute__((ext_vector_type(2)));

__device__ __forceinline__ float fdot2f(uint32 w, uint32 h, float acc) {
#if __has_builtin(__builtin_amdgcn_fdot2)
  return __builtin_amdgcn_fdot2(__builtin_bit_cast(half2_t, w),
                                __builtin_bit_cast(half2_t, h), acc, false);
#else
  half2_t a = __builtin_bit_cast(half2_t, w);
  half2_t b = __builtin_bit_cast(half2_t, h);
  return acc + (float)a[0]*(float)b[0] + (float)a[1]*(float)b[1];
#endif
}

__device__ __forceinline__ uint32 pack_h2(float x, float y) {
  _Float16 hx = (_Float16)x, hy = (_Float16)y;
  u16 ux = __builtin_bit_cast(u16, hx);
  u16 uy = __builtin_bit_cast(u16, hy);
  return (uint32)ux | ((uint32)uy << 16);
}

__device__ __forceinline__ uint4 pk4(const float* __restrict__ p) {
  return uint4{pack_h2(p[0],p[1]), pack_h2(p[2],p[3]),
               pack_h2(p[4],p[5]), pack_h2(p[6],p[7])};
}

__device__ __forceinline__ float sigm(float x) { return 1.0f/(1.0f + expf(-x)); }

// ---- AGPR storage (the other 256 regs of the gfx950 unified file) ----
#define AW(A, v)  asm volatile("v_accvgpr_write_b32 %0, %1" : "=a"(A) : "v"(v))
#define ARD(d, A) asm volatile("v_accvgpr_read_b32 %0, %1"  : "=v"(d) : "a"(A))

#define FOR12(M) M(0) M(1) M(2) M(3) M(4) M(5) M(6) M(7) M(8) M(9) M(10) M(11)
#define FOR80(M) M(0) M(1) M(2) M(3) M(4) M(5) M(6) M(7) M(8) M(9) \
  M(10) M(11) M(12) M(13) M(14) M(15) M(16) M(17) M(18) M(19) \
  M(20) M(21) M(22) M(23) M(24) M(25) M(26) M(27) M(28) M(29) \
  M(30) M(31) M(32) M(33) M(34) M(35) M(36) M(37) M(38) M(39) \
  M(40) M(41) M(42) M(43) M(44) M(45) M(46) M(47) M(48) M(49) \
  M(50) M(51) M(52) M(53) M(54) M(55) M(56) M(57) M(58) M(59) \
  M(60) M(61) M(62) M(63) M(64) M(65) M(66) M(67) M(68) M(69) \
  M(70) M(71) M(72) M(73) M(74) M(75) M(76) M(77) M(78) M(79)

// VGPR weights: k-words 0..47 of each gate row (12 uint4 per gate)
#define DV(j) uint4 R##j{}, Z##j{}, N##j{};
#define WV(j) { R##j = pk4(pr + 8*(j)); Z##j = pk4(pz + 8*(j)); N##j = pk4(pn + 8*(j)); }
// AGPR weights: k-words 48..127 (f16 pairs 96+2i) of each gate row
#define DA(i) uint32 AR##i, AZ##i, AN##i;
#define WA(i) { AW(AR##i, pack_h2(pr[96+2*(i)], pr[97+2*(i)])); \
                AW(AZ##i, pack_h2(pz[96+2*(i)], pz[97+2*(i)])); \
                AW(AN##i, pack_h2(pn[96+2*(i)], pn[97+2*(i)])); }

// dot step, VGPR part: h4[j] against R/Z/N j
#define VJ(j) { uint4 hp = h4[(j)]; \
  ar0=fdot2f(R##j.x,hp.x,ar0); ar1=fdot2f(R##j.y,hp.y,ar1); \
  ar0=fdot2f(R##j.z,hp.z,ar0); ar1=fdot2f(R##j.w,hp.w,ar1); \
  az0=fdot2f(Z##j.x,hp.x,az0); az1=fdot2f(Z##j.y,hp.y,az1); \
  az0=fdot2f(Z##j.z,hp.z,az0); az1=fdot2f(Z##j.w,hp.w,az1); \
  an0=fdot2f(N##j.x,hp.x,an0); an1=fdot2f(N##j.y,hp.y,an1); \
  an0=fdot2f(N##j.z,hp.z,an0); an1=fdot2f(N##j.w,hp.w,an1); }

// dot step, AGPR part: h4[12+m] against AGPR words i0..i3 of each gate
#define AJ(m, i0,i1,i2,i3) { uint4 hp = h4[12+(m)]; uint32 w0,w1,w2,w3; \
  ARD(w0, AR##i0); ARD(w1, AR##i1); ARD(w2, AR##i2); ARD(w3, AR##i3); \
  ar0=fdot2f(w0,hp.x,ar0); ar1=fdot2f(w1,hp.y,ar1); \
  ar0=fdot2f(w2,hp.z,ar0); ar1=fdot2f(w3,hp.w,ar1); \
  ARD(w0, AZ##i0); ARD(w1, AZ##i1); ARD(w2, AZ##i2); ARD(w3, AZ##i3); \
  az0=fdot2f(w0,hp.x,az0); az1=fdot2f(w1,hp.y,az1); \
  az0=fdot2f(w2,hp.z,az0); az1=fdot2f(w3,hp.w,az1); \
  ARD(w0, AN##i0); ARD(w1, AN##i1); ARD(w2, AN##i2); ARD(w3, AN##i3); \
  an0=fdot2f(w0,hp.x,an0); an1=fdot2f(w1,hp.y,an1); \
  an0=fdot2f(w2,hp.z,an0); an1=fdot2f(w3,hp.w,an1); }

#define AJ_ALL \
  AJ(0,0,1,2,3)     AJ(1,4,5,6,7)     AJ(2,8,9,10,11)   AJ(3,12,13,14,15)  \
  AJ(4,16,17,18,19) AJ(5,20,21,22,23) AJ(6,24,25,26,27) AJ(7,28,29,30,31)  \
  AJ(8,32,33,34,35) AJ(9,36,37,38,39) AJ(10,40,41,42,43) AJ(11,44,45,46,47)\
  AJ(12,48,49,50,51) AJ(13,52,53,54,55) AJ(14,56,57,58,59) AJ(15,60,61,62,63)\
  AJ(16,64,65,66,67) AJ(17,68,69,70,71) AJ(18,72,73,74,75) AJ(19,76,77,78,79)

// helper-WG input projection (b_hh folded for r/z gates)
__device__ __forceinline__ void xp_gemm(
    const float* __restrict__ src, const float* __restrict__ wih,
    const float* __restrict__ bih, const float* __restrict__ bhh,
    float* __restrict__ xpo, int wgi, int tid, float (*XcL)[256])
{
  const int t0 = wgi * 4;
  for (int r = tid; r < 1024; r += NTH) XcL[r >> 8][r & 255] = src[t0 * 256 + r];
  __syncthreads();
  for (int o = tid; o < 768; o += NTH) {
    const float* wr = wih + o * 256;
    float a0 = 0.f, a1 = 0.f, a2 = 0.f, a3 = 0.f;
#pragma unroll 4
    for (int k = 0; k < 256; ++k) {
      float w = wr[k];
      a0 += w * XcL[0][k]; a1 += w * XcL[1][k];
      a2 += w * XcL[2][k]; a3 += w * XcL[3][k];
    }
    float b = bih[o] + ((o < 512) ? bhh[o] : 0.f);
    xpo[(t0+0)*768+o] = a0+b; xpo[(t0+1)*768+o] = a1+b;
    xpo[(t0+2)*768+o] = a2+b; xpo[(t0+3)*768+o] = a3+b;
  }
  __syncthreads();
}

extern "C" __global__ void __launch_bounds__(NTH, 1)
__attribute__((amdgpu_waves_per_eu(1, 1)))
sed_kernel(const float* __restrict__ X,    const float* __restrict__ w1,
           const float* __restrict__ b1,   const float* __restrict__ w2,
           const float* __restrict__ b2,
           const float* __restrict__ ewih, const float* __restrict__ ewhh,
           const float* __restrict__ ebih, const float* __restrict__ ebhh,
           const float* __restrict__ dwih, const float* __restrict__ dwhh,
           const float* __restrict__ dbih, const float* __restrict__ dbhh,
           const float* __restrict__ fcw,  const float* __restrict__ fcb,
           float* __restrict__ out, unsigned char* __restrict__ ws)
{
  const int tid = threadIdx.x;
  const int wg  = blockIdx.x;
  uint32* bar_cnt = (uint32*)(ws);
  uint32* bar_rel = (uint32*)(ws + 128);
  float* xp = (float*)(ws + OFF_XP);
  float* Xc = (float*)(ws + OFF_XC);
  float* D  = (float*)(ws + OFF_D);
  float* y1 = (float*)(ws + OFF_Y1);

  __shared__ __align__(16) u16 h16d[2*256];   // double-buffered h (f16)
  __shared__ float XcL[4][256];
  __shared__ float hv[256], red[256], abuf[256], cbuf[256], pbuf[256];
  __shared__ float lbuf[26*8], la[32];

  unsigned round_ = 0;
  auto gbar = [&]() {
    __syncthreads();
    if (tid == 0) {
      unsigned old = __hip_atomic_fetch_add(bar_cnt, 1u, __ATOMIC_ACQ_REL,
                                            __HIP_MEMORY_SCOPE_AGENT);
      unsigned tgt = (round_ + 1u) * (unsigned)NWG;
      if (old + 1u == tgt)
        __hip_atomic_store(bar_rel, round_ + 1u, __ATOMIC_RELEASE,
                           __HIP_MEMORY_SCOPE_AGENT);
      while (__hip_atomic_load(bar_rel, __ATOMIC_ACQUIRE,
                               __HIP_MEMORY_SCOPE_AGENT) < round_ + 1u)
        __builtin_amdgcn_s_sleep(2);
    }
    round_ += 1u;
    __syncthreads();
  };

  const int u = tid;           // lane owns hidden unit u fully (rows r_u, z_u, n_u)
  FOR12(DV)                    // 36 uint4  = 144 VGPR weight words
  FOR80(DA)                    // 240 AGPR weight words (via inline-asm "a")
  float bn_ = 0.f, hreg = 0.f;

  auto loadW = [&](const float* __restrict__ whh, const float* __restrict__ bhh) {
    const float* pr = whh + u * 256;
    const float* pz = whh + (256 + u) * 256;
    const float* pn = whh + (512 + u) * 256;
    FOR12(WV)
    FOR80(WA)
    bn_ = bhh[512 + u];
  };

  // 256 sequential GRU cells; 1 barrier/cell (double-buffered h); lane-local cell.
  auto cells = [&](const float* __restrict__ xpb, float* __restrict__ dst,
                   bool relu) {
    int p = 0;
    for (int t = 0; t < 256; ++t) {
      const float* xpt = xpb + t * 768;
      float xr = xpt[u], xz = xpt[256 + u], xn = xpt[512 + u];
      const uint4* h4 = (const uint4*)(h16d + p * 256);
      float ar0=0.f, ar1=0.f, az0=0.f, az1=0.f, an0=0.f, an1=0.f;
      FOR12(VJ)                // k 0..95   from VGPR weights
      AJ_ALL                   // k 96..255 from AGPR weights
      float r    = sigm(xr + ar0 + ar1);          // b_r folded into xp
      float z    = sigm(xz + az0 + az1);          // b_z folded into xp
      float n    = tanhf(xn + r * (an0 + an1 + bn_));
      float hnew = (1.0f - z) * n + z * hreg;
      hreg = hnew;
      h16d[(p ^ 1) * 256 + u] = __builtin_bit_cast(u16, (_Float16)hnew);
      dst[t * 256 + u] = relu ? fmaxf(hnew, 0.0f) : hnew;
      __syncthreads();         // new buffer complete; old buffer reads done
      p ^= 1;
    }
  };

  // ---- P0a: y1[j][c] = w1[j]*x[c] + b1[j]   [128][512]
  for (int idx = wg * NTH + tid; idx < 128 * 512; idx += NWG * NTH) {
    int j = idx >> 9, c = idx & 511;
    y1[idx] = w1[j] * X[c] + b1[j];
  }
  gbar();

  // ---- P0b: seq[t][d] = y2[d][2t]
  for (int idx = wg * NTH + tid; idx < 256 * 256; idx += NWG * NTH) {
    int d = idx & 255, t = idx >> 8;
    const float* w2r = w2 + d * 128;
    float acc = b2[d];
#pragma unroll 4
    for (int j = 0; j < 128; ++j) acc += w2r[j] * y1[j * 512 + 2 * t];
    Xc[t * 256 + d] = acc;
  }
  gbar();

  // ---- P0c: helpers xp_enc; WG0 loads enc W_hh into VGPR+AGPR
  if (wg == 0) loadW(ewhh, ebhh);
  else         xp_gemm(Xc, ewih, ebih, ebhh, xp, wg - 1, tid, XcL);
  gbar();

  // ---- P1: encoder (256 cells) -> relu(h) into Xc
  if (wg == 0) {
    h16d[tid] = 0;             // seed h buffer 0
    hreg = 0.f;
    __syncthreads();
    cells(xp, Xc, true);
  }
  gbar();

  // ---- P2: helpers xp^0 from Xr; WG0 loads dec W_hh
  if (wg == 0) loadW(dwhh, dbhh);
  else         xp_gemm(Xc, dwih, dbih, dbhh, xp, wg - 1, tid, XcL);
  gbar();

  // ---- decoder: 256 outer rows
  for (int k = 0; k < 256; ++k) {
    if (wg == 0) cells(xp, D, false);
    gbar();

    if (wg == 0) {
      hv[tid] = D[255 * 256 + tid];              // h_new vector
      __syncthreads();
      {                                           // s_t = D[t,:]·h_new
        const float* dr = D + tid * 256;
        float p = 0.f;
#pragma unroll 4
        for (int q = 0; q < 256; ++q) p += dr[q] * hv[q];
        pbuf[tid] = p; red[tid] = p;
      }
      __syncthreads();
      for (int st = 128; st > 0; st >>= 1) {
        if (tid < st) red[tid] = fmaxf(red[tid], red[tid + st]);
        __syncthreads();
      }
      float m = red[0];
      __syncthreads();
      { float e = expf(pbuf[tid] - m); abuf[tid] = e; red[tid] = e; }
      __syncthreads();
      for (int st = 128; st > 0; st >>= 1) {
        if (tid < st) red[tid] += red[tid + st];
        __syncthreads();
      }
      float inv = 1.0f / red[0];
      __syncthreads();
      abuf[tid] *= inv;
      __syncthreads();
      {                                           // context vector
        float acc = abuf[0] * D[tid];
        for (int t = 1; t < 256; ++t) acc += abuf[t - 1] * D[t * 256 + tid];
        cbuf[tid] = acc;
      }
      __syncthreads();
      if (tid < 26 * 8) {                         // logits
        int j = tid >> 3, sgm = tid & 7;
        const float* fr   = fcw + j * 512 + sgm * 64;
        const float* vsrc = (sgm < 4) ? (hv + sgm * 64) : (cbuf + (sgm - 4) * 64);
        float p = 0.f;
#pragma unroll 4
        for (int q = 0; q < 64; ++q) p += fr[q] * vsrc[q];
        lbuf[tid] = p;
      }
      __syncthreads();
      if (tid < 26) {
        float l = fcb[tid];
#pragma unroll
        for (int s = 0; s < 8; ++s) l += lbuf[tid * 8 + s];
        la[tid] = l;
      }
      __syncthreads();
      if (tid == 0) {
        float m2 = la[0];
        for (int j = 1; j < 26; ++j) m2 = fmaxf(m2, la[j]);
        float sm = 0.f;
        for (int j = 0; j < 26; ++j) { float e = expf(la[j] - m2); la[j] = e; sm += e; }
        float ii = 1.0f / sm;
        for (int j = 0; j < 26; ++j) la[j] *= ii;
      }
      __syncthreads();
      if (tid < 26) out[k * 26 + tid] = la[tid];
      __syncthreads();
    } else if (k < 255) {
      xp_gemm(D, dwih, dbih, dbhh, xp, wg - 1, tid, XcL);
    }
    gbar();
  }
}

extern "C" void kernel_launch(void* const* d_in, const int* in_sizes, int n_in,
                              void* d_out, int out_size, void* d_ws, size_t ws_size,
                              hipStream_t stream) {
  (void)in_sizes; (void)n_in; (void)out_size; (void)ws_size;
  hipMemsetAsync(d_ws, 0, 1024, stream);
  sed_kernel<<<NWG, NTH, 0, stream>>>(
      (const float*)d_in[0],  (const float*)d_in[1],  (const float*)d_in[2],
      (const float*)d_in[3],  (const float*)d_in[4],  (const float*)d_in[5],
      (const float*)d_in[6],  (const float*)d_in[7],  (const float*)d_in[8],
      (const float*)d_in[9],  (const float*)d_in[10], (const float*)d_in[11],
      (const float*)d_in[12], (const float*)d_in[13], (const float*)d_in[14],
      (float*)d_out, (unsigned char*)d_ws);
}